// Round 14
// baseline (203.928 us; speedup 1.0000x reference)
//
#include <hip/hip_runtime.h>

#define NN 3072
#define FF 512
#define HH 8
#define DD 64
#define SLOPEV 0.2f

typedef __bf16  bf16x8 __attribute__((ext_vector_type(8)));
typedef short   s16x8  __attribute__((ext_vector_type(8)));
typedef float   f32x4  __attribute__((ext_vector_type(4)));
typedef unsigned long long u64;
typedef unsigned int u32;

#define MFMA16(a,b,c) __builtin_amdgcn_mfma_f32_16x16x32_bf16((a),(b),(c),0,0,0)

__device__ __forceinline__ short f2bf(float x){ __bf16 b=(__bf16)x; return __builtin_bit_cast(short,b); }
__device__ __forceinline__ float bf2f(short s){ return (float)__builtin_bit_cast(__bf16,s); }
__device__ __forceinline__ bf16x8 ldbf8(const short* p){ return __builtin_bit_cast(bf16x8, *(const s16x8*)p); }

// ---- K0: W[h][f][d] -> WT[h][d][f] bf16 hi/lo, plus wa = W @ a (fp32) ----
__global__ __launch_bounds__(64) void k_wt(const float* __restrict__ W, const float* __restrict__ a,
    short* __restrict__ wthi, short* __restrict__ wtlo,
    float* __restrict__ wasrc, float* __restrict__ wadst){
  int h = blockIdx.y, f0 = blockIdx.x*8, d = threadIdx.x;
  float asv = a[h*2*DD + d];
  float adv = a[h*2*DD + DD + d];
  s16x8 vh, vl;
  #pragma unroll
  for (int j=0;j<8;j++){
    float v = W[((size_t)h*FF + f0 + j)*DD + d];
    short s = f2bf(v); vh[j]=s; vl[j]=f2bf(v-bf2f(s));
    float ws_ = v*asv, wd_ = v*adv;
    #pragma unroll
    for (int m=1;m<64;m<<=1){ ws_ += __shfl_xor(ws_,m,64); wd_ += __shfl_xor(wd_,m,64); }
    if (d==0){ wasrc[h*FF+f0+j]=ws_; wadst[h*FF+f0+j]=wd_; }
  }
  size_t o = ((size_t)h*DD + d)*FF + f0;
  *(s16x8*)(wthi+o)=vh; *(s16x8*)(wtlo+o)=vl;
}

// ---- K0c: bit-pack adj via ballot (grid-stride) ----
__global__ __launch_bounds__(256) void k_pack(const int* __restrict__ adj, u64* __restrict__ padj){
  const int total = NN*NN;
  for (int idx = blockIdx.x*256 + threadIdx.x; idx < total; idx += gridDim.x*256){
    u64 b = __ballot(adj[idx] > 0);
    if ((threadIdx.x & 63) == 0) padj[idx>>6] = b;
  }
}

// ---- K1: src/dst for ALL heads, h read once per row ----
__global__ __launch_bounds__(256) void k_srcdst(const float* __restrict__ h,
    const float* __restrict__ wasrc, const float* __restrict__ wadst,
    float* __restrict__ src, float* __restrict__ dst){
  int n = blockIdx.x*4 + (threadIdx.x>>6);
  int lane = threadIdx.x & 63;
  const float* hp = h + (size_t)n*FF + lane*8;
  float4 x0 = *(const float4*)hp, x1 = *(const float4*)(hp+4);
  float xs[8] = {x0.x,x0.y,x0.z,x0.w,x1.x,x1.y,x1.z,x1.w};
  float ps[HH], pd[HH];
  #pragma unroll
  for (int hh=0; hh<HH; hh++){
    const float* sp = wasrc + (size_t)hh*FF + lane*8;
    const float* dp = wadst + (size_t)hh*FF + lane*8;
    float4 s0 = *(const float4*)sp, s1 = *(const float4*)(sp+4);
    float4 t0 = *(const float4*)dp, t1 = *(const float4*)(dp+4);
    ps[hh] = xs[0]*s0.x + xs[1]*s0.y + xs[2]*s0.z + xs[3]*s0.w
           + xs[4]*s1.x + xs[5]*s1.y + xs[6]*s1.z + xs[7]*s1.w;
    pd[hh] = xs[0]*t0.x + xs[1]*t0.y + xs[2]*t0.z + xs[3]*t0.w
           + xs[4]*t1.x + xs[5]*t1.y + xs[6]*t1.z + xs[7]*t1.w;
  }
  #pragma unroll
  for (int m=1;m<64;m<<=1){
    #pragma unroll
    for (int hh=0; hh<HH; hh++){ ps[hh] += __shfl_xor(ps[hh],m,64); pd[hh] += __shfl_xor(pd[hh],m,64); }
  }
  if (lane==0){
    #pragma unroll
    for (int hh=0; hh<HH; hh++){ src[hh*NN+n]=ps[hh]; dst[hh*NN+n]=pd[hh]; }
  }
}

// ---- K2: ht = h @ W[h]; fp32 h split in-register (3-term MFMA); bf16 htT stores ----
__global__ __launch_bounds__(128) void k_ht(const float* __restrict__ h,
    const short* __restrict__ wthi, const short* __restrict__ wtlo,
    short* __restrict__ hthi){
  __shared__ short tH[64][40];
  int hh = blockIdx.y, n0 = blockIdx.x*32;
  int w = threadIdx.x>>6, lane = threadIdx.x&63;
  int r15 = lane&15, g = lane>>4;
  int arow = n0 + w*16 + r15;
  f32x4 acc[4] = {{0.f,0.f,0.f,0.f},{0.f,0.f,0.f,0.f},{0.f,0.f,0.f,0.f},{0.f,0.f,0.f,0.f}};
  const float* ha = h + (size_t)arow*FF + g*8;
  for (int kk=0; kk<FF; kk+=32){
    float4 x0 = *(const float4*)(ha+kk), x1 = *(const float4*)(ha+kk+4);
    float xv[8] = {x0.x,x0.y,x0.z,x0.w,x1.x,x1.y,x1.z,x1.w};
    bf16x8 ahi, alo;
    #pragma unroll
    for (int e=0;e<8;e++){
      short s = f2bf(xv[e]);
      ahi[e] = __builtin_bit_cast(__bf16, s);
      alo[e] = (__bf16)(xv[e] - bf2f(s));
    }
    #pragma unroll
    for (int c=0;c<4;c++){
      size_t bo = ((size_t)hh*DD + c*16 + r15)*FF + g*8 + kk;
      bf16x8 bh = ldbf8(wthi + bo), bl = ldbf8(wtlo + bo);
      acc[c] = MFMA16(ahi,bh,acc[c]);
      acc[c] = MFMA16(ahi,bl,acc[c]);
      acc[c] = MFMA16(alo,bh,acc[c]);
    }
  }
  #pragma unroll
  for (int c=0;c<4;c++){
    #pragma unroll
    for (int r=0;r<4;r++){
      int dloc = c*16 + r15, nloc = w*16 + g*4 + r;
      tH[dloc][nloc] = f2bf(acc[c][r]);
    }
  }
  __syncthreads();
  int row = threadIdx.x>>1, half = threadIdx.x&1;
  size_t o = ((size_t)hh*DD + row)*NN + n0 + half*16;
  *(s16x8*)(hthi + o)     = *(const s16x8*)&tH[row][half*16];
  *(s16x8*)(hthi + o + 8) = *(const s16x8*)&tH[row][half*16+8];
}

// ---- K3: ZERO-BARRIER wave-local fused att+hp.
// 8 waves: wv = mq*2 + rg. Wave owns rows n0+rg*16+[0,16) x m-quarter mq*768+[0,768).
// p computed in-register in the exact MFMA A-frag layout (lane(r15,g) = p[r15][g*8+e]);
// B-frag = 16B contiguous htT read (16 rows x 64B/instr, L2-hot); att stored from a
// second store-layout p (redundant exp): per instr 16 rows x one FULL 64B line.
// No LDS / s_barrier / waitcnt in the main loop — only 2 barriers total.
__global__ __launch_bounds__(512, 8) void k_att(const u64* __restrict__ padj,
    const float* __restrict__ src, const float* __restrict__ dst,
    const short* __restrict__ hthi, float* __restrict__ dout){
  __shared__ float rs[8][16];
  __shared__ float hpbuf[4][2][16][68];   // [mq][rg][row][d] padded
  const size_t OUTOFF = (size_t)NN*HH*DD;
  int bid = blockIdx.x;
  int h = bid & 7, n0 = (bid >> 3) * 32;
  int t = threadIdx.x, wv = t>>6, lane = t&63;
  int r15 = lane&15, g = lane>>4;
  int rg = wv&1, mq = wv>>1;
  int prow = n0 + rg*16 + r15;
  float srcv = src[h*NN + prow];
  const float* dsth = dst + h*NN;
  const u32* abits = (const u32*)(padj + (size_t)prow*(NN/64));
  const int mq24 = mq*24, mq768 = mq*768;

  // ---- sweep A: partial row sums over this wave's m-quarter ----
  float psum = 0.f;
  #pragma unroll 2
  for (int s=0;s<24;s++){
    u32 bits = abits[mq24+s];
    const float* dp = dsth + mq768 + s*32 + g*8;
    float4 d0 = *(const float4*)dp, d1 = *(const float4*)(dp+4);
    float dj[8] = {d0.x,d0.y,d0.z,d0.w,d1.x,d1.y,d1.z,d1.w};
    #pragma unroll
    for (int e=0;e<8;e++){
      float ev = srcv + dj[e];
      ev = fmaxf(ev, SLOPEV*ev);
      psum += ((bits >> (g*8+e)) & 1u) ? __expf(ev) : 0.f;
    }
  }
  psum += __shfl_xor(psum,16,64); psum += __shfl_xor(psum,32,64);
  if (lane < 16) rs[wv][lane] = psum;
  __syncthreads();
  float tot = rs[rg][r15] + rs[2+rg][r15] + rs[4+rg][r15] + rs[6+rg][r15];
  float inv = (tot > 0.f) ? 1.f/tot : (1.f/(float)NN);
  bool am = !(tot > 0.f);

  // ---- sweep B: free-running, no barriers ----
  f32x4 acc[4] = {{0.f,0.f,0.f,0.f},{0.f,0.f,0.f,0.f},{0.f,0.f,0.f,0.f},{0.f,0.f,0.f,0.f}};
  float* attrow = dout + OUTOFF + ((size_t)(h*NN + prow))*NN + mq768;
  const short* gb = hthi + ((size_t)(h*DD) + r15)*NN + mq768 + g*8;

  #pragma unroll 2
  for (int s=0;s<24;s++){
    int mb = s*32;
    u32 bits = abits[mq24+s];
    const float* dpa = dsth + mq768 + mb;
    // store-layout p: instr s0 covers m [0,16) (g*4), s1 covers [16,32)
    float4 dsa = *(const float4*)(dpa + g*4);
    float4 dsb = *(const float4*)(dpa + 16 + g*4);
    // A-layout p: m = g*8+e
    float4 dma = *(const float4*)(dpa + g*8);
    float4 dmb = *(const float4*)(dpa + g*8 + 4);

    f32x4 o0, o1;
    #pragma unroll
    for (int e=0;e<4;e++){
      float ev = srcv + ((const float*)&dsa)[e];
      ev = fmaxf(ev, SLOPEV*ev);
      float p = ((bits >> (g*4+e)) & 1u) ? __expf(ev) : 0.f;
      if (am) p = 1.f;
      o0[e] = p * inv;
      float ev2 = srcv + ((const float*)&dsb)[e];
      ev2 = fmaxf(ev2, SLOPEV*ev2);
      float p2 = ((bits >> (16+g*4+e)) & 1u) ? __expf(ev2) : 0.f;
      if (am) p2 = 1.f;
      o1[e] = p2 * inv;
    }
    __builtin_nontemporal_store(o0, (f32x4*)(attrow + mb + g*4));
    __builtin_nontemporal_store(o1, (f32x4*)(attrow + mb + 16 + g*4));

    bf16x8 af;
    #pragma unroll
    for (int e=0;e<4;e++){
      float ev = srcv + ((const float*)&dma)[e];
      ev = fmaxf(ev, SLOPEV*ev);
      float p = ((bits >> (g*8+e)) & 1u) ? __expf(ev) : 0.f;
      if (am) p = 1.f;
      af[e] = (__bf16)(p * inv);
      float ev2 = srcv + ((const float*)&dmb)[e];
      ev2 = fmaxf(ev2, SLOPEV*ev2);
      float p2 = ((bits >> (g*8+4+e)) & 1u) ? __expf(ev2) : 0.f;
      if (am) p2 = 1.f;
      af[4+e] = (__bf16)(p2 * inv);
    }
    #pragma unroll
    for (int cb=0;cb<4;cb++){
      bf16x8 bh = ldbf8(gb + (size_t)cb*16*NN + mb);
      acc[cb] = MFMA16(af, bh, acc[cb]);
    }
  }

  // ---- combine across the 4 m-quarter waves ----
  #pragma unroll
  for (int cb=0;cb<4;cb++){
    #pragma unroll
    for (int reg=0;reg<4;reg++)
      hpbuf[mq][rg][g*4+reg][cb*16+r15] = acc[cb][reg];
  }
  __syncthreads();
  int orow = t>>4, dc = (t&15)*4;
  int org = orow>>4, orr = orow&15;
  f32x4 osum;
  #pragma unroll
  for (int k=0;k<4;k++)
    osum[k] = hpbuf[0][org][orr][dc+k] + hpbuf[1][org][orr][dc+k]
            + hpbuf[2][org][orr][dc+k] + hpbuf[3][org][orr][dc+k];
  size_t ob = (size_t)(n0+orow)*(HH*DD) + h*DD + dc;
  __builtin_nontemporal_store(osum, (f32x4*)(dout+ob));
}

extern "C" void kernel_launch(void* const* d_in, const int* in_sizes, int n_in,
                              void* d_out, int out_size, void* d_ws, size_t ws_size,
                              hipStream_t stream) {
  const float* h   = (const float*)d_in[0];
  const int*   adj = (const int*)d_in[1];
  const float* W   = (const float*)d_in[2];
  const float* a   = (const float*)d_in[3];
  float* out = (float*)d_out;

  short* wthi = (short*)d_ws;
  short* wtlo = wthi + (size_t)HH*DD*FF;
  short* hthi = wtlo + (size_t)HH*DD*FF;
  float* wasrc= (float*)(hthi + (size_t)HH*DD*NN);
  float* wadst= wasrc + HH*FF;
  float* srcb = wadst + HH*FF;
  float* dstb = srcb + HH*NN;
  u64*   padj = (u64*)(dstb + HH*NN);

  k_wt    <<<dim3(FF/8, HH), 64, 0, stream>>>(W, a, wthi, wtlo, wasrc, wadst);
  k_pack  <<<dim3(2048), 256, 0, stream>>>(adj, padj);
  k_srcdst<<<dim3(NN/4), 256, 0, stream>>>(h, wasrc, wadst, srcb, dstb);
  k_ht    <<<dim3(NN/32, HH), 128, 0, stream>>>(h, wthi, wtlo, hthi);
  k_att   <<<dim3(NN/32*HH), 512, 0, stream>>>(padj, srcb, dstb, hthi, out);
}

// Round 15
// 194.791 us; speedup vs baseline: 1.0469x; 1.0469x over previous
//
#include <hip/hip_runtime.h>

#define NN 3072
#define FF 512
#define HH 8
#define DD 64
#define SLOPEV 0.2f

typedef __bf16  bf16x8 __attribute__((ext_vector_type(8)));
typedef short   s16x8  __attribute__((ext_vector_type(8)));
typedef float   f32x4  __attribute__((ext_vector_type(4)));
typedef unsigned long long u64;
typedef unsigned int u32;

#define MFMA16(a,b,c) __builtin_amdgcn_mfma_f32_16x16x32_bf16((a),(b),(c),0,0,0)

__device__ __forceinline__ short f2bf(float x){ __bf16 b=(__bf16)x; return __builtin_bit_cast(short,b); }
__device__ __forceinline__ float bf2f(short s){ return (float)__builtin_bit_cast(__bf16,s); }
__device__ __forceinline__ bf16x8 ldbf8(const short* p){ return __builtin_bit_cast(bf16x8, *(const s16x8*)p); }

// ---- K0: W[h][f][d] -> WT[h][d][f] bf16 hi/lo, plus wa = W @ a (fp32) ----
__global__ __launch_bounds__(64) void k_wt(const float* __restrict__ W, const float* __restrict__ a,
    short* __restrict__ wthi, short* __restrict__ wtlo,
    float* __restrict__ wasrc, float* __restrict__ wadst){
  int h = blockIdx.y, f0 = blockIdx.x*8, d = threadIdx.x;
  float asv = a[h*2*DD + d];
  float adv = a[h*2*DD + DD + d];
  s16x8 vh, vl;
  #pragma unroll
  for (int j=0;j<8;j++){
    float v = W[((size_t)h*FF + f0 + j)*DD + d];
    short s = f2bf(v); vh[j]=s; vl[j]=f2bf(v-bf2f(s));
    float ws_ = v*asv, wd_ = v*adv;
    #pragma unroll
    for (int m=1;m<64;m<<=1){ ws_ += __shfl_xor(ws_,m,64); wd_ += __shfl_xor(wd_,m,64); }
    if (d==0){ wasrc[h*FF+f0+j]=ws_; wadst[h*FF+f0+j]=wd_; }
  }
  size_t o = ((size_t)h*DD + d)*FF + f0;
  *(s16x8*)(wthi+o)=vh; *(s16x8*)(wtlo+o)=vl;
}

// ---- K0c: bit-pack adj via ballot (grid-stride) ----
__global__ __launch_bounds__(256) void k_pack(const int* __restrict__ adj, u64* __restrict__ padj){
  const int total = NN*NN;
  for (int idx = blockIdx.x*256 + threadIdx.x; idx < total; idx += gridDim.x*256){
    u64 b = __ballot(adj[idx] > 0);
    if ((threadIdx.x & 63) == 0) padj[idx>>6] = b;
  }
}

// ---- K1: src/dst for ALL heads, h read once per row ----
__global__ __launch_bounds__(256) void k_srcdst(const float* __restrict__ h,
    const float* __restrict__ wasrc, const float* __restrict__ wadst,
    float* __restrict__ src, float* __restrict__ dst){
  int n = blockIdx.x*4 + (threadIdx.x>>6);
  int lane = threadIdx.x & 63;
  const float* hp = h + (size_t)n*FF + lane*8;
  float4 x0 = *(const float4*)hp, x1 = *(const float4*)(hp+4);
  float xs[8] = {x0.x,x0.y,x0.z,x0.w,x1.x,x1.y,x1.z,x1.w};
  float ps[HH], pd[HH];
  #pragma unroll
  for (int hh=0; hh<HH; hh++){
    const float* sp = wasrc + (size_t)hh*FF + lane*8;
    const float* dp = wadst + (size_t)hh*FF + lane*8;
    float4 s0 = *(const float4*)sp, s1 = *(const float4*)(sp+4);
    float4 t0 = *(const float4*)dp, t1 = *(const float4*)(dp+4);
    ps[hh] = xs[0]*s0.x + xs[1]*s0.y + xs[2]*s0.z + xs[3]*s0.w
           + xs[4]*s1.x + xs[5]*s1.y + xs[6]*s1.z + xs[7]*s1.w;
    pd[hh] = xs[0]*t0.x + xs[1]*t0.y + xs[2]*t0.z + xs[3]*t0.w
           + xs[4]*t1.x + xs[5]*t1.y + xs[6]*t1.z + xs[7]*t1.w;
  }
  #pragma unroll
  for (int m=1;m<64;m<<=1){
    #pragma unroll
    for (int hh=0; hh<HH; hh++){ ps[hh] += __shfl_xor(ps[hh],m,64); pd[hh] += __shfl_xor(pd[hh],m,64); }
  }
  if (lane==0){
    #pragma unroll
    for (int hh=0; hh<HH; hh++){ src[hh*NN+n]=ps[hh]; dst[hh*NN+n]=pd[hh]; }
  }
}

// ---- K2: ht = h @ W[h]; fp32 h split in-register (3-term MFMA); bf16 htT stores ----
__global__ __launch_bounds__(128) void k_ht(const float* __restrict__ h,
    const short* __restrict__ wthi, const short* __restrict__ wtlo,
    short* __restrict__ hthi){
  __shared__ short tH[64][40];
  int hh = blockIdx.y, n0 = blockIdx.x*32;
  int w = threadIdx.x>>6, lane = threadIdx.x&63;
  int r15 = lane&15, g = lane>>4;
  int arow = n0 + w*16 + r15;
  f32x4 acc[4] = {{0.f,0.f,0.f,0.f},{0.f,0.f,0.f,0.f},{0.f,0.f,0.f,0.f},{0.f,0.f,0.f,0.f}};
  const float* ha = h + (size_t)arow*FF + g*8;
  for (int kk=0; kk<FF; kk+=32){
    float4 x0 = *(const float4*)(ha+kk), x1 = *(const float4*)(ha+kk+4);
    float xv[8] = {x0.x,x0.y,x0.z,x0.w,x1.x,x1.y,x1.z,x1.w};
    bf16x8 ahi, alo;
    #pragma unroll
    for (int e=0;e<8;e++){
      short s = f2bf(xv[e]);
      ahi[e] = __builtin_bit_cast(__bf16, s);
      alo[e] = (__bf16)(xv[e] - bf2f(s));
    }
    #pragma unroll
    for (int c=0;c<4;c++){
      size_t bo = ((size_t)hh*DD + c*16 + r15)*FF + g*8 + kk;
      bf16x8 bh = ldbf8(wthi + bo), bl = ldbf8(wtlo + bo);
      acc[c] = MFMA16(ahi,bh,acc[c]);
      acc[c] = MFMA16(ahi,bl,acc[c]);
      acc[c] = MFMA16(alo,bh,acc[c]);
    }
  }
  #pragma unroll
  for (int c=0;c<4;c++){
    #pragma unroll
    for (int r=0;r<4;r++){
      int dloc = c*16 + r15, nloc = w*16 + g*4 + r;
      tH[dloc][nloc] = f2bf(acc[c][r]);
    }
  }
  __syncthreads();
  int row = threadIdx.x>>1, half = threadIdx.x&1;
  size_t o = ((size_t)hh*DD + row)*NN + n0 + half*16;
  *(s16x8*)(hthi + o)     = *(const s16x8*)&tH[row][half*16];
  *(s16x8*)(hthi + o + 8) = *(const s16x8*)&tH[row][half*16+8];
}

// ---- K3: zero-main-loop-barrier wave-local att+hp, REGISTER-DOUBLE-BUFFERED B.
// Wave (rg,mq) owns rows n0+rg*16+[0,16) x m-quarter. p built in MFMA A-layout
// in-register; B-frags for step s+1 loaded to VGPRs at top of step s (latency
// hidden under exp block); att stored full-64B-line nt. 2 barriers total.
__global__ __launch_bounds__(512, 4) void k_att(const u64* __restrict__ padj,
    const float* __restrict__ src, const float* __restrict__ dst,
    const short* __restrict__ hthi, float* __restrict__ dout){
  __shared__ float rs[8][16];
  __shared__ float hpbuf[4][2][16][68];   // [mq][rg][row][d] padded
  const size_t OUTOFF = (size_t)NN*HH*DD;
  int bid = blockIdx.x;
  int h = bid & 7, n0 = (bid >> 3) * 32;
  int t = threadIdx.x, wv = t>>6, lane = t&63;
  int r15 = lane&15, g = lane>>4;
  int rg = wv&1, mq = wv>>1;
  int prow = n0 + rg*16 + r15;
  float srcv = src[h*NN + prow];
  const float* dsth = dst + h*NN;
  const u32* abits = (const u32*)(padj + (size_t)prow*(NN/64));
  const int mq24 = mq*24, mq768 = mq*768;

  // ---- sweep A: partial row sums over this wave's m-quarter ----
  float psum = 0.f;
  #pragma unroll 2
  for (int s=0;s<24;s++){
    u32 bits = abits[mq24+s];
    const float* dp = dsth + mq768 + s*32 + g*8;
    float4 d0 = *(const float4*)dp, d1 = *(const float4*)(dp+4);
    float dj[8] = {d0.x,d0.y,d0.z,d0.w,d1.x,d1.y,d1.z,d1.w};
    #pragma unroll
    for (int e=0;e<8;e++){
      float ev = srcv + dj[e];
      ev = fmaxf(ev, SLOPEV*ev);
      psum += ((bits >> (g*8+e)) & 1u) ? __expf(ev) : 0.f;
    }
  }
  psum += __shfl_xor(psum,16,64); psum += __shfl_xor(psum,32,64);
  if (lane < 16) rs[wv][lane] = psum;
  __syncthreads();
  float tot = rs[rg][r15] + rs[2+rg][r15] + rs[4+rg][r15] + rs[6+rg][r15];
  float inv = (tot > 0.f) ? 1.f/tot : (1.f/(float)NN);
  bool am = !(tot > 0.f);

  // ---- sweep B: free-running; B-frag double-buffered in VGPRs ----
  f32x4 acc[4] = {{0.f,0.f,0.f,0.f},{0.f,0.f,0.f,0.f},{0.f,0.f,0.f,0.f},{0.f,0.f,0.f,0.f}};
  float* attrow = dout + OUTOFF + ((size_t)(h*NN + prow))*NN + mq768;
  const short* gb = hthi + ((size_t)(h*DD) + r15)*NN + mq768 + g*8;

  bf16x8 bcur0 = ldbf8(gb);
  bf16x8 bcur1 = ldbf8(gb + (size_t)16*NN);
  bf16x8 bcur2 = ldbf8(gb + (size_t)32*NN);
  bf16x8 bcur3 = ldbf8(gb + (size_t)48*NN);

  #pragma unroll 2
  for (int s=0;s<24;s++){
    int mb = s*32;
    int mbn = (s+1 < 24) ? (s+1)*32 : 23*32;   // clamped (last iter loads dead data)
    // prefetch next B-frags into registers (consumed NEXT iteration)
    bf16x8 bn0 = ldbf8(gb + mbn);
    bf16x8 bn1 = ldbf8(gb + (size_t)16*NN + mbn);
    bf16x8 bn2 = ldbf8(gb + (size_t)32*NN + mbn);
    bf16x8 bn3 = ldbf8(gb + (size_t)48*NN + mbn);

    u32 bits = abits[mq24+s];
    const float* dpa = dsth + mq768 + mb;
    // store-layout dst slices (full 64B line coverage per instr)
    float4 dsa = *(const float4*)(dpa + g*4);
    float4 dsb = *(const float4*)(dpa + 16 + g*4);
    // A-layout dst slices
    float4 dma = *(const float4*)(dpa + g*8);
    float4 dmb = *(const float4*)(dpa + g*8 + 4);

    f32x4 o0, o1;
    #pragma unroll
    for (int e=0;e<4;e++){
      float ev = srcv + ((const float*)&dsa)[e];
      ev = fmaxf(ev, SLOPEV*ev);
      float p = ((bits >> (g*4+e)) & 1u) ? __expf(ev) : 0.f;
      if (am) p = 1.f;
      o0[e] = p * inv;
      float ev2 = srcv + ((const float*)&dsb)[e];
      ev2 = fmaxf(ev2, SLOPEV*ev2);
      float p2 = ((bits >> (16+g*4+e)) & 1u) ? __expf(ev2) : 0.f;
      if (am) p2 = 1.f;
      o1[e] = p2 * inv;
    }
    __builtin_nontemporal_store(o0, (f32x4*)(attrow + mb + g*4));
    __builtin_nontemporal_store(o1, (f32x4*)(attrow + mb + 16 + g*4));

    bf16x8 af;
    #pragma unroll
    for (int e=0;e<4;e++){
      float ev = srcv + ((const float*)&dma)[e];
      ev = fmaxf(ev, SLOPEV*ev);
      float p = ((bits >> (g*8+e)) & 1u) ? __expf(ev) : 0.f;
      if (am) p = 1.f;
      af[e] = (__bf16)(p * inv);
      float ev2 = srcv + ((const float*)&dmb)[e];
      ev2 = fmaxf(ev2, SLOPEV*ev2);
      float p2 = ((bits >> (g*8+4+e)) & 1u) ? __expf(ev2) : 0.f;
      if (am) p2 = 1.f;
      af[4+e] = (__bf16)(p2 * inv);
    }
    acc[0] = MFMA16(af, bcur0, acc[0]);
    acc[1] = MFMA16(af, bcur1, acc[1]);
    acc[2] = MFMA16(af, bcur2, acc[2]);
    acc[3] = MFMA16(af, bcur3, acc[3]);
    bcur0 = bn0; bcur1 = bn1; bcur2 = bn2; bcur3 = bn3;
  }

  // ---- combine across the 4 m-quarter waves ----
  #pragma unroll
  for (int cb=0;cb<4;cb++){
    #pragma unroll
    for (int reg=0;reg<4;reg++)
      hpbuf[mq][rg][g*4+reg][cb*16+r15] = acc[cb][reg];
  }
  __syncthreads();
  int orow = t>>4, dc = (t&15)*4;
  int org = orow>>4, orr = orow&15;
  f32x4 osum;
  #pragma unroll
  for (int k=0;k<4;k++)
    osum[k] = hpbuf[0][org][orr][dc+k] + hpbuf[1][org][orr][dc+k]
            + hpbuf[2][org][orr][dc+k] + hpbuf[3][org][orr][dc+k];
  size_t ob = (size_t)(n0+orow)*(HH*DD) + h*DD + dc;
  __builtin_nontemporal_store(osum, (f32x4*)(dout+ob));
}

extern "C" void kernel_launch(void* const* d_in, const int* in_sizes, int n_in,
                              void* d_out, int out_size, void* d_ws, size_t ws_size,
                              hipStream_t stream) {
  const float* h   = (const float*)d_in[0];
  const int*   adj = (const int*)d_in[1];
  const float* W   = (const float*)d_in[2];
  const float* a   = (const float*)d_in[3];
  float* out = (float*)d_out;

  short* wthi = (short*)d_ws;
  short* wtlo = wthi + (size_t)HH*DD*FF;
  short* hthi = wtlo + (size_t)HH*DD*FF;
  float* wasrc= (float*)(hthi + (size_t)HH*DD*NN);
  float* wadst= wasrc + HH*FF;
  float* srcb = wadst + HH*FF;
  float* dstb = srcb + HH*NN;
  u64*   padj = (u64*)(dstb + HH*NN);

  k_wt    <<<dim3(FF/8, HH), 64, 0, stream>>>(W, a, wthi, wtlo, wasrc, wadst);
  k_pack  <<<dim3(2048), 256, 0, stream>>>(adj, padj);
  k_srcdst<<<dim3(NN/4), 256, 0, stream>>>(h, wasrc, wadst, srcb, dstb);
  k_ht    <<<dim3(NN/32, HH), 128, 0, stream>>>(h, wthi, wtlo, hthi);
  k_att   <<<dim3(NN/32*HH), 512, 0, stream>>>(padj, srcb, dstb, hthi, out);
}

// Round 16
// 139.862 us; speedup vs baseline: 1.4581x; 1.3927x over previous
//
#include <hip/hip_runtime.h>

#define NN 3072
#define FF 512
#define HH 8
#define DD 64
#define SLOPEV 0.2f
#define CH 128
#define NC (NN/CH)    // 24

typedef __bf16  bf16x8 __attribute__((ext_vector_type(8)));
typedef __bf16  bf16x4 __attribute__((ext_vector_type(4)));
typedef short   s16x8  __attribute__((ext_vector_type(8)));
typedef float   f32x4  __attribute__((ext_vector_type(4)));
typedef unsigned long long u64;

#define MFMA16(a,b,c) __builtin_amdgcn_mfma_f32_16x16x32_bf16((a),(b),(c),0,0,0)

__device__ __forceinline__ short f2bf(float x){ __bf16 b=(__bf16)x; return __builtin_bit_cast(short,b); }
__device__ __forceinline__ float bf2f(short s){ return (float)__builtin_bit_cast(__bf16,s); }
__device__ __forceinline__ bf16x8 ldbf8(const short* p){ return __builtin_bit_cast(bf16x8, *(const s16x8*)p); }

__device__ __forceinline__ void gload16(const void* g, void* l){
  __builtin_amdgcn_global_load_lds(
      (const __attribute__((address_space(1))) void*)(uintptr_t)g,
      (__attribute__((address_space(3))) void*)(uint32_t)(uintptr_t)l, 16, 0, 0);
}

// ==== D1: k_wt (blocks 0..127, 4 wave-units each) || k_pack (blocks 128..1151) ====
__global__ __launch_bounds__(256) void k_prep1(const float* __restrict__ W, const float* __restrict__ a,
    const int* __restrict__ adj,
    short* __restrict__ wthi, short* __restrict__ wtlo,
    float* __restrict__ wasrc, float* __restrict__ wadst, u64* __restrict__ padj){
  int bid = blockIdx.x, t = threadIdx.x;
  if (bid < 128){
    int uid = bid*4 + (t>>6);               // 512 units: (h, f0)
    int h = uid>>6, f0 = (uid&63)*8, d = t&63;
    float asv = a[h*2*DD + d];
    float adv = a[h*2*DD + DD + d];
    s16x8 vh, vl;
    #pragma unroll
    for (int j=0;j<8;j++){
      float v = W[((size_t)h*FF + f0 + j)*DD + d];
      short s = f2bf(v); vh[j]=s; vl[j]=f2bf(v-bf2f(s));
      float ws_ = v*asv, wd_ = v*adv;
      #pragma unroll
      for (int m=1;m<64;m<<=1){ ws_ += __shfl_xor(ws_,m,64); wd_ += __shfl_xor(wd_,m,64); }
      if (d==0){ wasrc[h*FF+f0+j]=ws_; wadst[h*FF+f0+j]=wd_; }
    }
    size_t o = ((size_t)h*DD + d)*FF + f0;
    *(s16x8*)(wthi+o)=vh; *(s16x8*)(wtlo+o)=vl;
  } else {
    const int total = NN*NN;
    for (int idx = (bid-128)*256 + t; idx < total; idx += 1024*256){
      u64 b = __ballot(adj[idx] > 0);
      if ((t & 63) == 0) padj[idx>>6] = b;
    }
  }
}

// ==== D2: k_srcdst (blocks 0..767) || k_ht (blocks 768..1151, 2 units each) ====
__global__ __launch_bounds__(256) void k_prep2(const float* __restrict__ h,
    const short* __restrict__ wthi, const short* __restrict__ wtlo,
    const float* __restrict__ wasrc, const float* __restrict__ wadst,
    float* __restrict__ src, float* __restrict__ dst, short* __restrict__ hthi){
  __shared__ short tH[2][64][40];
  int bid = blockIdx.x, t = threadIdx.x;
  if (bid < 768){
    int n = bid*4 + (t>>6);
    int lane = t & 63;
    const float* hp = h + (size_t)n*FF + lane*8;
    float4 x0 = *(const float4*)hp, x1 = *(const float4*)(hp+4);
    float xs[8] = {x0.x,x0.y,x0.z,x0.w,x1.x,x1.y,x1.z,x1.w};
    float ps[HH], pd[HH];
    #pragma unroll
    for (int hh=0; hh<HH; hh++){
      const float* sp = wasrc + (size_t)hh*FF + lane*8;
      const float* dp = wadst + (size_t)hh*FF + lane*8;
      float4 s0 = *(const float4*)sp, s1 = *(const float4*)(sp+4);
      float4 t0 = *(const float4*)dp, t1 = *(const float4*)(dp+4);
      ps[hh] = xs[0]*s0.x + xs[1]*s0.y + xs[2]*s0.z + xs[3]*s0.w
             + xs[4]*s1.x + xs[5]*s1.y + xs[6]*s1.z + xs[7]*s1.w;
      pd[hh] = xs[0]*t0.x + xs[1]*t0.y + xs[2]*t0.z + xs[3]*t0.w
             + xs[4]*t1.x + xs[5]*t1.y + xs[6]*t1.z + xs[7]*t1.w;
    }
    #pragma unroll
    for (int m=1;m<64;m<<=1){
      #pragma unroll
      for (int hh=0; hh<HH; hh++){ ps[hh] += __shfl_xor(ps[hh],m,64); pd[hh] += __shfl_xor(pd[hh],m,64); }
    }
    if (lane==0){
      #pragma unroll
      for (int hh=0; hh<HH; hh++){ src[hh*NN+n]=ps[hh]; dst[hh*NN+n]=pd[hh]; }
    }
  } else {
    int uu = t>>7, tid = t&127;
    int unit = (bid-768)*2 + uu;            // 768 units: (hh, n0)
    int hh = unit/96, n0 = (unit%96)*32;
    int w = tid>>6, lane = tid&63;
    int r15 = lane&15, g = lane>>4;
    int arow = n0 + w*16 + r15;
    f32x4 acc[4] = {{0.f,0.f,0.f,0.f},{0.f,0.f,0.f,0.f},{0.f,0.f,0.f,0.f},{0.f,0.f,0.f,0.f}};
    const float* ha = h + (size_t)arow*FF + g*8;
    for (int kk=0; kk<FF; kk+=32){
      float4 x0 = *(const float4*)(ha+kk), x1 = *(const float4*)(ha+kk+4);
      float xv[8] = {x0.x,x0.y,x0.z,x0.w,x1.x,x1.y,x1.z,x1.w};
      bf16x8 ahi, alo;
      #pragma unroll
      for (int e=0;e<8;e++){
        short s = f2bf(xv[e]);
        ahi[e] = __builtin_bit_cast(__bf16, s);
        alo[e] = (__bf16)(xv[e] - bf2f(s));
      }
      #pragma unroll
      for (int c=0;c<4;c++){
        size_t bo = ((size_t)hh*DD + c*16 + r15)*FF + g*8 + kk;
        bf16x8 bh = ldbf8(wthi + bo), bl = ldbf8(wtlo + bo);
        acc[c] = MFMA16(ahi,bh,acc[c]);
        acc[c] = MFMA16(ahi,bl,acc[c]);
        acc[c] = MFMA16(alo,bh,acc[c]);
      }
    }
    #pragma unroll
    for (int c=0;c<4;c++){
      #pragma unroll
      for (int r=0;r<4;r++){
        int dloc = c*16 + r15, nloc = w*16 + g*4 + r;
        tH[uu][dloc][nloc] = f2bf(acc[c][r]);
      }
    }
    __syncthreads();
    int row = tid>>1, half = tid&1;
    size_t o = ((size_t)hh*DD + row)*NN + n0 + half*16;
    *(s16x8*)(hthi + o)     = *(const s16x8*)&tH[uu][row][half*16];
    *(s16x8*)(hthi + o + 8) = *(const s16x8*)&tH[uu][row][half*16+8];
  }
}

// ==== D3: k_att — fused 2-sweep att+hp, CH=128 (24 iters, 48 barriers) ====
// thread (r=t>>4, j=t&15) owns m = {c*128+j*4..+4} U {c*128+64+j*4..+4}.
// Staging: 2x gload16 (rows 0-31, 32-63), source slot pre-swizzled (t&15)^(drow&7).
// vmem/iter = 7 (2 stage + 1 bits + 2 dv + 2 store) -> vmcnt(12) at barrier-1
// retires exactly prev iter's 2 staging ops; 2 iters of stores stay in flight.
__global__ __launch_bounds__(512, 6) void k_att(const u64* __restrict__ padj,
    const float* __restrict__ src, const float* __restrict__ dst,
    const short* __restrict__ hthi, float* __restrict__ dout){
  __shared__ short hA[64][CH], hB[64][CH];   // 16KB each
  __shared__ short pA[32][CH], pB[32][CH];   // 8KB each
  const size_t OUTOFF = (size_t)NN*HH*DD;
  int bid = blockIdx.x;
  int h = bid & 7, n0 = (bid >> 3) * 32;
  int t = threadIdx.x;
  int r = t>>4, j = t&15;
  int nrow = n0 + r;
  float srcv = src[h*NN + nrow];
  const float* dsth = dst + h*NN;
  const u64* arow = padj + (size_t)nrow*(NN/64);

  int wv = t>>6, lane = t&63, r15 = lane&15, g = lane>>4;
  int cblk = wv&3, nh = wv>>2;
  int drow = t>>4;                            // 0..31
  int sslot = (t&15) ^ (drow&7);
  const short* ghA = hthi + ((size_t)(h*DD) + drow)*NN + sslot*8;
  const short* ghB = hthi + ((size_t)(h*DD) + drow + 32)*NN + sslot*8;

  // stage chunk 0 early; sweep A's consumed loads retire it before sweep B
  gload16(ghA, &hA[wv*4][0]);
  gload16(ghB, &hA[32 + wv*4][0]);

  // ---- sweep A: row sums ----
  float psum = 0.f;
  for (int c=0;c<NC;c++){
    u64 w0 = arow[c*2], w1 = arow[c*2+1];
    const float* dp = dsth + c*CH + j*4;
    float4 d0 = *(const float4*)dp, d1 = *(const float4*)(dp+64);
    float dj[8] = {d0.x,d0.y,d0.z,d0.w,d1.x,d1.y,d1.z,d1.w};
    #pragma unroll
    for (int e=0;e<8;e++){
      float ev = srcv + dj[e];
      ev = fmaxf(ev, SLOPEV*ev);
      u64 bits = (e<4) ? w0 : w1;
      float p = ((bits >> (j*4 + (e&3))) & 1ull) ? __expf(ev) : 0.f;
      psum += p;
    }
  }
  #pragma unroll
  for (int m=1;m<16;m<<=1) psum += __shfl_xor(psum, m, 64);
  float inv = (psum > 0.f) ? 1.f/psum : (1.f/(float)NN);
  bool am = !(psum > 0.f);

  // ---- sweep B ----
  f32x4 acc = {0.f,0.f,0.f,0.f};
  float* attrow = dout + OUTOFF + ((size_t)(h*NN + nrow))*NN;
  int aoff0 = (cblk*16 + r15)*(CH*2);
  int boff0 = (nh*16 + r15)*(CH*2);
  int csw   = (r15&7)<<4;
  int xw    = (r&7)<<4;
  int pof0  = r*(CH*2) + ((j*8) ^ xw);
  int pof1  = r*(CH*2) + ((128 + j*8) ^ xw);
  const float* dvp = dsth + j*4;

  u64 w0 = arow[0], w1 = arow[1];
  float4 dva = *(const float4*)dvp;
  float4 dvb = *(const float4*)(dvp + 64);

  for (int c=0;c<NC;c++){
    short (*hc)[CH] = (c&1)?hB:hA;
    short (*hn)[CH] = (c&1)?hA:hB;
    short (*pc)[CH] = (c&1)?pB:pA;

    // vmem 1,2: stage chunk c+1 (clamped dead-restage on last iter)
    int cn = (c+1 < NC) ? c+1 : NC-1;
    gload16(ghA + cn*CH, &hn[wv*4][0]);
    gload16(ghB + cn*CH, &hn[32 + wv*4][0]);
    // vmem 3,4,5: next bits (one 16B) + next dv halves
    u64 w0n = arow[cn*2], w1n = arow[cn*2+1];
    float4 dva_n = *(const float4*)(dvp + cn*CH);
    float4 dvb_n = *(const float4*)(dvp + cn*CH + 64);

    // compute p (8 values), att nt-stores (vmem 6,7), p -> LDS (2x 8B)
    float o[8];
    #pragma unroll
    for (int e=0;e<4;e++){
      float ev = srcv + ((const float*)&dva)[e];
      ev = fmaxf(ev, SLOPEV*ev);
      float p = ((w0 >> (j*4 + e)) & 1ull) ? __expf(ev) : 0.f;
      if (am) p = 1.f;
      o[e] = p * inv;
      float ev2 = srcv + ((const float*)&dvb)[e];
      ev2 = fmaxf(ev2, SLOPEV*ev2);
      float p2 = ((w1 >> (j*4 + e)) & 1ull) ? __expf(ev2) : 0.f;
      if (am) p2 = 1.f;
      o[4+e] = p2 * inv;
    }
    f32x4 s0 = {o[0],o[1],o[2],o[3]};
    f32x4 s1 = {o[4],o[5],o[6],o[7]};
    __builtin_nontemporal_store(s0, (f32x4*)(attrow + c*CH + j*4));
    __builtin_nontemporal_store(s1, (f32x4*)(attrow + c*CH + 64 + j*4));
    bf16x4 p0, p1;
    #pragma unroll
    for (int e=0;e<4;e++){ p0[e] = (__bf16)o[e]; p1[e] = (__bf16)o[4+e]; }
    *(bf16x4*)((char*)pc + pof0) = p0;
    *(bf16x4*)((char*)pc + pof1) = p1;

    // barrier 1: vmcnt(12) -> prev iter's staging complete; stores in flight
    __builtin_amdgcn_sched_barrier(0);
    asm volatile("s_waitcnt vmcnt(12) lgkmcnt(0)" ::: "memory");
    __builtin_amdgcn_sched_barrier(0);
    __builtin_amdgcn_s_barrier();
    __builtin_amdgcn_sched_barrier(0);

    // MFMA chunk c: 4 k-slices
    const char* hcB = (const char*)hc;
    const char* pcB = (const char*)pc;
    #pragma unroll
    for (int ks=0;ks<4;ks++){
      int kb = (ks*64 + g*16) ^ csw;
      bf16x8 bf = *(const bf16x8*)(pcB + boff0 + kb);
      bf16x8 ah = *(const bf16x8*)(hcB + aoff0 + kb);
      acc = MFMA16(ah, bf, acc);
    }
    // barrier 2 (bare): protect hc/pc from next iteration's overwrite
    asm volatile("" ::: "memory");
    __builtin_amdgcn_s_barrier();
    __builtin_amdgcn_sched_barrier(0);

    w0 = w0n; w1 = w1n; dva = dva_n; dvb = dvb_n;
  }

  // ---- epilogue ----
  int n = n0 + nh*16 + r15;
  size_t ob = (size_t)n*(HH*DD) + h*DD + cblk*16 + g*4;
  __builtin_nontemporal_store(acc, (f32x4*)(dout+ob));
}

extern "C" void kernel_launch(void* const* d_in, const int* in_sizes, int n_in,
                              void* d_out, int out_size, void* d_ws, size_t ws_size,
                              hipStream_t stream) {
  const float* h   = (const float*)d_in[0];
  const int*   adj = (const int*)d_in[1];
  const float* W   = (const float*)d_in[2];
  const float* a   = (const float*)d_in[3];
  float* out = (float*)d_out;

  short* wthi = (short*)d_ws;
  short* wtlo = wthi + (size_t)HH*DD*FF;
  short* hthi = wtlo + (size_t)HH*DD*FF;
  float* wasrc= (float*)(hthi + (size_t)HH*DD*NN);
  float* wadst= wasrc + HH*FF;
  float* srcb = wadst + HH*FF;
  float* dstb = srcb + HH*NN;
  u64*   padj = (u64*)(dstb + HH*NN);

  k_prep1<<<dim3(1152), 256, 0, stream>>>(W, a, adj, wthi, wtlo, wasrc, wadst, padj);
  k_prep2<<<dim3(1152), 256, 0, stream>>>(h, wthi, wtlo, wasrc, wadst, srcb, dstb, hthi);
  k_att  <<<dim3(NN/32*HH), 512, 0, stream>>>(padj, srcb, dstb, hthi, out);
}

// Round 18
// 138.896 us; speedup vs baseline: 1.4682x; 1.0070x over previous
//
#include <hip/hip_runtime.h>

#define NN 3072
#define FF 512
#define HH 8
#define DD 64
#define SLOPEV 0.2f
#define CH 128
#define NC (NN/CH)    // 24

typedef __bf16  bf16x8 __attribute__((ext_vector_type(8)));
typedef __bf16  bf16x4 __attribute__((ext_vector_type(4)));
typedef short   s16x8  __attribute__((ext_vector_type(8)));
typedef float   f32x4  __attribute__((ext_vector_type(4)));
typedef unsigned long long u64;

#define MFMA16(a,b,c) __builtin_amdgcn_mfma_f32_16x16x32_bf16((a),(b),(c),0,0,0)

__device__ __forceinline__ short f2bf(float x){ __bf16 b=(__bf16)x; return __builtin_bit_cast(short,b); }
__device__ __forceinline__ float bf2f(short s){ return (float)__builtin_bit_cast(__bf16,s); }
__device__ __forceinline__ bf16x8 ldbf8(const short* p){ return __builtin_bit_cast(bf16x8, *(const s16x8*)p); }

__device__ __forceinline__ void gload16(const void* g, void* l){
  __builtin_amdgcn_global_load_lds(
      (const __attribute__((address_space(1))) void*)(uintptr_t)g,
      (__attribute__((address_space(3))) void*)(uint32_t)(uintptr_t)l, 16, 0, 0);
}

// ==== D1: k_wt (blocks 0..127, 4 wave-units each) || k_pack (blocks 128..1151) ====
__global__ __launch_bounds__(256) void k_prep1(const float* __restrict__ W, const float* __restrict__ a,
    const int* __restrict__ adj,
    short* __restrict__ wthi, short* __restrict__ wtlo,
    float* __restrict__ wasrc, float* __restrict__ wadst, u64* __restrict__ padj){
  int bid = blockIdx.x, t = threadIdx.x;
  if (bid < 128){
    int uid = bid*4 + (t>>6);               // 512 units: (h, f0)
    int h = uid>>6, f0 = (uid&63)*8, d = t&63;
    float asv = a[h*2*DD + d];
    float adv = a[h*2*DD + DD + d];
    s16x8 vh, vl;
    #pragma unroll
    for (int j=0;j<8;j++){
      float v = W[((size_t)h*FF + f0 + j)*DD + d];
      short s = f2bf(v); vh[j]=s; vl[j]=f2bf(v-bf2f(s));
      float ws_ = v*asv, wd_ = v*adv;
      #pragma unroll
      for (int m=1;m<64;m<<=1){ ws_ += __shfl_xor(ws_,m,64); wd_ += __shfl_xor(wd_,m,64); }
      if (d==0){ wasrc[h*FF+f0+j]=ws_; wadst[h*FF+f0+j]=wd_; }
    }
    size_t o = ((size_t)h*DD + d)*FF + f0;
    *(s16x8*)(wthi+o)=vh; *(s16x8*)(wtlo+o)=vl;
  } else {
    const int total = NN*NN;
    for (int idx = (bid-128)*256 + t; idx < total; idx += 1024*256){
      u64 b = __ballot(adj[idx] > 0);
      if ((t & 63) == 0) padj[idx>>6] = b;
    }
  }
}

// ==== D2: k_srcdst (blocks 0..767) || k_ht (blocks 768..1151, 2 units each) ====
__global__ __launch_bounds__(256) void k_prep2(const float* __restrict__ h,
    const short* __restrict__ wthi, const short* __restrict__ wtlo,
    const float* __restrict__ wasrc, const float* __restrict__ wadst,
    float* __restrict__ src, float* __restrict__ dst, short* __restrict__ hthi){
  __shared__ short tH[2][64][40];
  int bid = blockIdx.x, t = threadIdx.x;
  if (bid < 768){
    int n = bid*4 + (t>>6);
    int lane = t & 63;
    const float* hp = h + (size_t)n*FF + lane*8;
    float4 x0 = *(const float4*)hp, x1 = *(const float4*)(hp+4);
    float xs[8] = {x0.x,x0.y,x0.z,x0.w,x1.x,x1.y,x1.z,x1.w};
    float ps[HH], pd[HH];
    #pragma unroll
    for (int hh=0; hh<HH; hh++){
      const float* sp = wasrc + (size_t)hh*FF + lane*8;
      const float* dp = wadst + (size_t)hh*FF + lane*8;
      float4 s0 = *(const float4*)sp, s1 = *(const float4*)(sp+4);
      float4 t0 = *(const float4*)dp, t1 = *(const float4*)(dp+4);
      ps[hh] = xs[0]*s0.x + xs[1]*s0.y + xs[2]*s0.z + xs[3]*s0.w
             + xs[4]*s1.x + xs[5]*s1.y + xs[6]*s1.z + xs[7]*s1.w;
      pd[hh] = xs[0]*t0.x + xs[1]*t0.y + xs[2]*t0.z + xs[3]*t0.w
             + xs[4]*t1.x + xs[5]*t1.y + xs[6]*t1.z + xs[7]*t1.w;
    }
    #pragma unroll
    for (int m=1;m<64;m<<=1){
      #pragma unroll
      for (int hh=0; hh<HH; hh++){ ps[hh] += __shfl_xor(ps[hh],m,64); pd[hh] += __shfl_xor(pd[hh],m,64); }
    }
    if (lane==0){
      #pragma unroll
      for (int hh=0; hh<HH; hh++){ src[hh*NN+n]=ps[hh]; dst[hh*NN+n]=pd[hh]; }
    }
  } else {
    int uu = t>>7, tid = t&127;
    int unit = (bid-768)*2 + uu;            // 768 units: (hh, n0)
    int hh = unit/96, n0 = (unit%96)*32;
    int w = tid>>6, lane = tid&63;
    int r15 = lane&15, g = lane>>4;
    int arow = n0 + w*16 + r15;
    f32x4 acc[4] = {{0.f,0.f,0.f,0.f},{0.f,0.f,0.f,0.f},{0.f,0.f,0.f,0.f},{0.f,0.f,0.f,0.f}};
    const float* ha = h + (size_t)arow*FF + g*8;
    for (int kk=0; kk<FF; kk+=32){
      float4 x0 = *(const float4*)(ha+kk), x1 = *(const float4*)(ha+kk+4);
      float xv[8] = {x0.x,x0.y,x0.z,x0.w,x1.x,x1.y,x1.z,x1.w};
      bf16x8 ahi, alo;
      #pragma unroll
      for (int e=0;e<8;e++){
        short s = f2bf(xv[e]);
        ahi[e] = __builtin_bit_cast(__bf16, s);
        alo[e] = (__bf16)(xv[e] - bf2f(s));
      }
      #pragma unroll
      for (int c=0;c<4;c++){
        size_t bo = ((size_t)hh*DD + c*16 + r15)*FF + g*8 + kk;
        bf16x8 bh = ldbf8(wthi + bo), bl = ldbf8(wtlo + bo);
        acc[c] = MFMA16(ahi,bh,acc[c]);
        acc[c] = MFMA16(ahi,bl,acc[c]);
        acc[c] = MFMA16(alo,bh,acc[c]);
      }
    }
    #pragma unroll
    for (int c=0;c<4;c++){
      #pragma unroll
      for (int r=0;r<4;r++){
        int dloc = c*16 + r15, nloc = w*16 + g*4 + r;
        tH[uu][dloc][nloc] = f2bf(acc[c][r]);
      }
    }
    __syncthreads();
    int row = tid>>1, half = tid&1;
    size_t o = ((size_t)hh*DD + row)*NN + n0 + half*16;
    *(s16x8*)(hthi + o)     = *(const s16x8*)&tH[uu][row][half*16];
    *(s16x8*)(hthi + o + 8) = *(const s16x8*)&tH[uu][row][half*16+8];
  }
}

// ==== D3: k_att — fused 2-sweep att+hp, CH=128, single barrier/chunk (24 total).
// Staging for c+1 issued AFTER MFMA(c) and PINNED with sched_barrier(0) so the
// vmem issue order per iter is exactly [stage x2][3 loads + 2 stores][vmcnt(5)]:
// vmcnt(5) retires precisely the staging pair (r17 bug: unpinned staging could
// sink past the next iter's loads and escape the count).
__global__ __launch_bounds__(512, 6) void k_att(const u64* __restrict__ padj,
    const float* __restrict__ src, const float* __restrict__ dst,
    const short* __restrict__ hthi, float* __restrict__ dout){
  __shared__ short hA[64][CH], hB[64][CH];   // 16KB each
  __shared__ short pA[32][CH], pB[32][CH];   // 8KB each
  const size_t OUTOFF = (size_t)NN*HH*DD;
  int bid = blockIdx.x;
  int h = bid & 7, n0 = (bid >> 3) * 32;
  int t = threadIdx.x;
  int r = t>>4, j = t&15;
  int nrow = n0 + r;
  float srcv = src[h*NN + nrow];
  const float* dsth = dst + h*NN;
  const u64* arow = padj + (size_t)nrow*(NN/64);

  int wv = t>>6, lane = t&63, r15 = lane&15, g = lane>>4;
  int cblk = wv&3, nh = wv>>2;
  int drow = t>>4;                            // 0..31
  int sslot = (t&15) ^ (drow&7);
  const short* ghA = hthi + ((size_t)(h*DD) + drow)*NN + sslot*8;
  const short* ghB = hthi + ((size_t)(h*DD) + drow + 32)*NN + sslot*8;

  // stage chunk 0 early (pinned); sweep A's consumed loads retire it
  gload16(ghA, &hA[wv*4][0]);
  gload16(ghB, &hA[32 + wv*4][0]);
  __builtin_amdgcn_sched_barrier(0);

  // ---- sweep A: row sums ----
  float psum = 0.f;
  for (int c=0;c<NC;c++){
    u64 w0 = arow[c*2], w1 = arow[c*2+1];
    const float* dp = dsth + c*CH + j*4;
    float4 d0 = *(const float4*)dp, d1 = *(const float4*)(dp+64);
    float dj[8] = {d0.x,d0.y,d0.z,d0.w,d1.x,d1.y,d1.z,d1.w};
    #pragma unroll
    for (int e=0;e<8;e++){
      float ev = srcv + dj[e];
      ev = fmaxf(ev, SLOPEV*ev);
      u64 bits = (e<4) ? w0 : w1;
      float p = ((bits >> (j*4 + (e&3))) & 1ull) ? __expf(ev) : 0.f;
      psum += p;
    }
  }
  #pragma unroll
  for (int m=1;m<16;m<<=1) psum += __shfl_xor(psum, m, 64);
  float inv = (psum > 0.f) ? 1.f/psum : (1.f/(float)NN);
  bool am = !(psum > 0.f);

  // ---- sweep B: single barrier per chunk; staging pinned at loop bottom ----
  f32x4 acc = {0.f,0.f,0.f,0.f};
  float* attrow = dout + OUTOFF + ((size_t)(h*NN + nrow))*NN;
  int aoff0 = (cblk*16 + r15)*(CH*2);
  int boff0 = (nh*16 + r15)*(CH*2);
  int csw   = (r15&7)<<4;
  int xw    = (r&7)<<4;
  int pof0  = r*(CH*2) + ((j*8) ^ xw);
  int pof1  = r*(CH*2) + ((128 + j*8) ^ xw);
  const float* dvp = dsth + j*4;

  u64 w0 = arow[0], w1 = arow[1];
  float4 dva = *(const float4*)dvp;
  float4 dvb = *(const float4*)(dvp + 64);

  for (int c=0;c<NC;c++){
    short (*hc)[CH] = (c&1)?hB:hA;
    short (*hn)[CH] = (c&1)?hA:hB;
    short (*pc)[CH] = (c&1)?pB:pA;

    // prefetch next bits + dv halves (3 vmem loads)
    int cn = (c+1 < NC) ? c+1 : NC-1;
    u64 w0n = arow[cn*2], w1n = arow[cn*2+1];
    float4 dva_n = *(const float4*)(dvp + cn*CH);
    float4 dvb_n = *(const float4*)(dvp + cn*CH + 64);

    // compute p (8 values), att nt-stores (2 vmem), p -> LDS (2x 8B)
    float o[8];
    #pragma unroll
    for (int e=0;e<4;e++){
      float ev = srcv + ((const float*)&dva)[e];
      ev = fmaxf(ev, SLOPEV*ev);
      float p = ((w0 >> (j*4 + e)) & 1ull) ? __expf(ev) : 0.f;
      if (am) p = 1.f;
      o[e] = p * inv;
      float ev2 = srcv + ((const float*)&dvb)[e];
      ev2 = fmaxf(ev2, SLOPEV*ev2);
      float p2 = ((w1 >> (j*4 + e)) & 1ull) ? __expf(ev2) : 0.f;
      if (am) p2 = 1.f;
      o[4+e] = p2 * inv;
    }
    f32x4 s0 = {o[0],o[1],o[2],o[3]};
    f32x4 s1 = {o[4],o[5],o[6],o[7]};
    __builtin_nontemporal_store(s0, (f32x4*)(attrow + c*CH + j*4));
    __builtin_nontemporal_store(s1, (f32x4*)(attrow + c*CH + 64 + j*4));
    bf16x4 p0, p1;
    #pragma unroll
    for (int e=0;e<4;e++){ p0[e] = (__bf16)o[e]; p1[e] = (__bf16)o[4+e]; }
    *(bf16x4*)((char*)pc + pof0) = p0;
    *(bf16x4*)((char*)pc + pof1) = p1;

    // THE barrier: vmcnt(5) retires staging(c) (issued+pinned at bottom of c-1)
    __builtin_amdgcn_sched_barrier(0);
    asm volatile("s_waitcnt vmcnt(5) lgkmcnt(0)" ::: "memory");
    __builtin_amdgcn_sched_barrier(0);
    __builtin_amdgcn_s_barrier();
    __builtin_amdgcn_sched_barrier(0);

    // MFMA chunk c: 4 k-slices
    const char* hcB = (const char*)hc;
    const char* pcB = (const char*)pc;
    #pragma unroll
    for (int ks=0;ks<4;ks++){
      int kb = (ks*64 + g*16) ^ csw;
      bf16x8 bf = *(const bf16x8*)(pcB + boff0 + kb);
      bf16x8 ah = *(const bf16x8*)(hcB + aoff0 + kb);
      acc = MFMA16(ah, bf, acc);
    }

    // staging for chunk c+1 AFTER the MFMA (WAR-safe: ordered by barrier(c)),
    // PINNED so it cannot sink past the next iteration's loads/stores.
    if (c+1 < NC){
      gload16(ghA + (c+1)*CH, &hn[wv*4][0]);
      gload16(ghB + (c+1)*CH, &hn[32 + wv*4][0]);
    }
    __builtin_amdgcn_sched_barrier(0);

    w0 = w0n; w1 = w1n; dva = dva_n; dvb = dvb_n;
  }

  // ---- epilogue ----
  int n = n0 + nh*16 + r15;
  size_t ob = (size_t)n*(HH*DD) + h*DD + cblk*16 + g*4;
  __builtin_nontemporal_store(acc, (f32x4*)(dout+ob));
}

extern "C" void kernel_launch(void* const* d_in, const int* in_sizes, int n_in,
                              void* d_out, int out_size, void* d_ws, size_t ws_size,
                              hipStream_t stream) {
  const float* h   = (const float*)d_in[0];
  const int*   adj = (const int*)d_in[1];
  const float* W   = (const float*)d_in[2];
  const float* a   = (const float*)d_in[3];
  float* out = (float*)d_out;

  short* wthi = (short*)d_ws;
  short* wtlo = wthi + (size_t)HH*DD*FF;
  short* hthi = wtlo + (size_t)HH*DD*FF;
  float* wasrc= (float*)(hthi + (size_t)HH*DD*NN);
  float* wadst= wasrc + HH*FF;
  float* srcb = wadst + HH*FF;
  float* dstb = srcb + HH*NN;
  u64*   padj = (u64*)(dstb + HH*NN);

  k_prep1<<<dim3(1152), 256, 0, stream>>>(W, a, adj, wthi, wtlo, wasrc, wadst, padj);
  k_prep2<<<dim3(1152), 256, 0, stream>>>(h, wthi, wtlo, wasrc, wadst, srcb, dstb, hthi);
  k_att  <<<dim3(NN/32*HH), 512, 0, stream>>>(padj, srcb, dstb, hthi, out);
}

// Round 19
// 136.405 us; speedup vs baseline: 1.4950x; 1.0183x over previous
//
#include <hip/hip_runtime.h>

#define NN 3072
#define FF 512
#define HH 8
#define DD 64
#define SLOPEV 0.2f
#define CH 128
#define NC (NN/CH)    // 24

typedef __bf16  bf16x8 __attribute__((ext_vector_type(8)));
typedef __bf16  bf16x4 __attribute__((ext_vector_type(4)));
typedef short   s16x8  __attribute__((ext_vector_type(8)));
typedef float   f32x4  __attribute__((ext_vector_type(4)));
typedef unsigned long long u64;

#define MFMA16(a,b,c) __builtin_amdgcn_mfma_f32_16x16x32_bf16((a),(b),(c),0,0,0)

__device__ __forceinline__ short f2bf(float x){ __bf16 b=(__bf16)x; return __builtin_bit_cast(short,b); }
__device__ __forceinline__ float bf2f(short s){ return (float)__builtin_bit_cast(__bf16,s); }
__device__ __forceinline__ bf16x8 ldbf8(const short* p){ return __builtin_bit_cast(bf16x8, *(const s16x8*)p); }

__device__ __forceinline__ void gload16(const void* g, void* l){
  __builtin_amdgcn_global_load_lds(
      (const __attribute__((address_space(1))) void*)(uintptr_t)g,
      (__attribute__((address_space(3))) void*)(uint32_t)(uintptr_t)l, 16, 0, 0);
}

// ==== D1: k_wt-split (blocks 0..127) || k_pack (blocks 128..1151) ====
// k_wt no longer computes wa (src/dst moved into k_ht's fp32 epilogue).
__global__ __launch_bounds__(256) void k_prep1(const float* __restrict__ W,
    const int* __restrict__ adj,
    short* __restrict__ wthi, short* __restrict__ wtlo, u64* __restrict__ padj){
  int bid = blockIdx.x, t = threadIdx.x;
  if (bid < 128){
    int uid = bid*4 + (t>>6);               // 512 units: (h, f0)
    int h = uid>>6, f0 = (uid&63)*8, d = t&63;
    s16x8 vh, vl;
    #pragma unroll
    for (int j=0;j<8;j++){
      float v = W[((size_t)h*FF + f0 + j)*DD + d];
      short s = f2bf(v); vh[j]=s; vl[j]=f2bf(v-bf2f(s));
    }
    size_t o = ((size_t)h*DD + d)*FF + f0;
    *(s16x8*)(wthi+o)=vh; *(s16x8*)(wtlo+o)=vl;
  } else {
    const int total = NN*NN;
    for (int idx = (bid-128)*256 + t; idx < total; idx += 1024*256){
      u64 b = __ballot(adj[idx] > 0);
      if ((t & 63) == 0) padj[idx>>6] = b;
    }
  }
}

// ==== D2: k_ht (384 blocks, 2 units each) with fused src/dst epilogue ====
// acc[c][r] = ht[n0+16w+4g+r][c*16+r15] in fp32 (3-term split MFMA) BEFORE
// rounding; src[n] = sum_d acc*a_src[d] via per-thread partial + 16-lane
// shfl_xor reduce. Then bf16 htT store via LDS transpose (as before).
__global__ __launch_bounds__(256) void k_prep2(const float* __restrict__ h,
    const short* __restrict__ wthi, const short* __restrict__ wtlo,
    const float* __restrict__ a,
    float* __restrict__ src, float* __restrict__ dst, short* __restrict__ hthi){
  __shared__ short tH[2][64][40];
  int bid = blockIdx.x, t = threadIdx.x;
  int uu = t>>7, tid = t&127;
  int unit = bid*2 + uu;                    // 768 units: (hh, n0)
  int hh = unit/96, n0 = (unit%96)*32;
  int w = tid>>6, lane = tid&63;
  int r15 = lane&15, g = lane>>4;
  int arow = n0 + w*16 + r15;
  f32x4 acc[4] = {{0.f,0.f,0.f,0.f},{0.f,0.f,0.f,0.f},{0.f,0.f,0.f,0.f},{0.f,0.f,0.f,0.f}};
  const float* ha = h + (size_t)arow*FF + g*8;
  for (int kk=0; kk<FF; kk+=32){
    float4 x0 = *(const float4*)(ha+kk), x1 = *(const float4*)(ha+kk+4);
    float xv[8] = {x0.x,x0.y,x0.z,x0.w,x1.x,x1.y,x1.z,x1.w};
    bf16x8 ahi, alo;
    #pragma unroll
    for (int e=0;e<8;e++){
      short s = f2bf(xv[e]);
      ahi[e] = __builtin_bit_cast(__bf16, s);
      alo[e] = (__bf16)(xv[e] - bf2f(s));
    }
    #pragma unroll
    for (int c=0;c<4;c++){
      size_t bo = ((size_t)hh*DD + c*16 + r15)*FF + g*8 + kk;
      bf16x8 bh = ldbf8(wthi + bo), bl = ldbf8(wtlo + bo);
      acc[c] = MFMA16(ahi,bh,acc[c]);
      acc[c] = MFMA16(ahi,bl,acc[c]);
      acc[c] = MFMA16(alo,bh,acc[c]);
    }
  }

  // ---- src/dst epilogue (fp32-accurate logits) ----
  float asv[4], adv[4];
  #pragma unroll
  for (int c=0;c<4;c++){
    asv[c] = a[hh*2*DD + c*16 + r15];
    adv[c] = a[hh*2*DD + DD + c*16 + r15];
  }
  #pragma unroll
  for (int r=0;r<4;r++){
    float ps = acc[0][r]*asv[0] + acc[1][r]*asv[1] + acc[2][r]*asv[2] + acc[3][r]*asv[3];
    float pd = acc[0][r]*adv[0] + acc[1][r]*adv[1] + acc[2][r]*adv[2] + acc[3][r]*adv[3];
    #pragma unroll
    for (int m=1;m<16;m<<=1){ ps += __shfl_xor(ps,m,64); pd += __shfl_xor(pd,m,64); }
    if (r15 == 0){
      int n = n0 + w*16 + g*4 + r;
      src[hh*NN + n] = ps;
      dst[hh*NN + n] = pd;
    }
  }

  // ---- bf16 htT store via LDS transpose ----
  #pragma unroll
  for (int c=0;c<4;c++){
    #pragma unroll
    for (int r=0;r<4;r++){
      int dloc = c*16 + r15, nloc = w*16 + g*4 + r;
      tH[uu][dloc][nloc] = f2bf(acc[c][r]);
    }
  }
  __syncthreads();
  int row = tid>>1, half = tid&1;
  size_t o = ((size_t)hh*DD + row)*NN + n0 + half*16;
  *(s16x8*)(hthi + o)     = *(const s16x8*)&tH[uu][row][half*16];
  *(s16x8*)(hthi + o + 8) = *(const s16x8*)&tH[uu][row][half*16+8];
}

// ==== D3: k_att — identical to round 18 (best known) ====
__global__ __launch_bounds__(512, 6) void k_att(const u64* __restrict__ padj,
    const float* __restrict__ src, const float* __restrict__ dst,
    const short* __restrict__ hthi, float* __restrict__ dout){
  __shared__ short hA[64][CH], hB[64][CH];   // 16KB each
  __shared__ short pA[32][CH], pB[32][CH];   // 8KB each
  const size_t OUTOFF = (size_t)NN*HH*DD;
  int bid = blockIdx.x;
  int h = bid & 7, n0 = (bid >> 3) * 32;
  int t = threadIdx.x;
  int r = t>>4, j = t&15;
  int nrow = n0 + r;
  float srcv = src[h*NN + nrow];
  const float* dsth = dst + h*NN;
  const u64* arow = padj + (size_t)nrow*(NN/64);

  int wv = t>>6, lane = t&63, r15 = lane&15, g = lane>>4;
  int cblk = wv&3, nh = wv>>2;
  int drow = t>>4;                            // 0..31
  int sslot = (t&15) ^ (drow&7);
  const short* ghA = hthi + ((size_t)(h*DD) + drow)*NN + sslot*8;
  const short* ghB = hthi + ((size_t)(h*DD) + drow + 32)*NN + sslot*8;

  // stage chunk 0 early (pinned); sweep A's consumed loads retire it
  gload16(ghA, &hA[wv*4][0]);
  gload16(ghB, &hA[32 + wv*4][0]);
  __builtin_amdgcn_sched_barrier(0);

  // ---- sweep A: row sums ----
  float psum = 0.f;
  for (int c=0;c<NC;c++){
    u64 w0 = arow[c*2], w1 = arow[c*2+1];
    const float* dp = dsth + c*CH + j*4;
    float4 d0 = *(const float4*)dp, d1 = *(const float4*)(dp+64);
    float dj[8] = {d0.x,d0.y,d0.z,d0.w,d1.x,d1.y,d1.z,d1.w};
    #pragma unroll
    for (int e=0;e<8;e++){
      float ev = srcv + dj[e];
      ev = fmaxf(ev, SLOPEV*ev);
      u64 bits = (e<4) ? w0 : w1;
      float p = ((bits >> (j*4 + (e&3))) & 1ull) ? __expf(ev) : 0.f;
      psum += p;
    }
  }
  #pragma unroll
  for (int m=1;m<16;m<<=1) psum += __shfl_xor(psum, m, 64);
  float inv = (psum > 0.f) ? 1.f/psum : (1.f/(float)NN);
  bool am = !(psum > 0.f);

  // ---- sweep B: single barrier per chunk; staging pinned at loop bottom ----
  f32x4 acc = {0.f,0.f,0.f,0.f};
  float* attrow = dout + OUTOFF + ((size_t)(h*NN + nrow))*NN;
  int aoff0 = (cblk*16 + r15)*(CH*2);
  int boff0 = (nh*16 + r15)*(CH*2);
  int csw   = (r15&7)<<4;
  int xw    = (r&7)<<4;
  int pof0  = r*(CH*2) + ((j*8) ^ xw);
  int pof1  = r*(CH*2) + ((128 + j*8) ^ xw);
  const float* dvp = dsth + j*4;

  u64 w0 = arow[0], w1 = arow[1];
  float4 dva = *(const float4*)dvp;
  float4 dvb = *(const float4*)(dvp + 64);

  for (int c=0;c<NC;c++){
    short (*hc)[CH] = (c&1)?hB:hA;
    short (*hn)[CH] = (c&1)?hA:hB;
    short (*pc)[CH] = (c&1)?pB:pA;

    // prefetch next bits + dv halves (3 vmem loads)
    int cn = (c+1 < NC) ? c+1 : NC-1;
    u64 w0n = arow[cn*2], w1n = arow[cn*2+1];
    float4 dva_n = *(const float4*)(dvp + cn*CH);
    float4 dvb_n = *(const float4*)(dvp + cn*CH + 64);

    // compute p (8 values), att nt-stores (2 vmem), p -> LDS (2x 8B)
    float o[8];
    #pragma unroll
    for (int e=0;e<4;e++){
      float ev = srcv + ((const float*)&dva)[e];
      ev = fmaxf(ev, SLOPEV*ev);
      float p = ((w0 >> (j*4 + e)) & 1ull) ? __expf(ev) : 0.f;
      if (am) p = 1.f;
      o[e] = p * inv;
      float ev2 = srcv + ((const float*)&dvb)[e];
      ev2 = fmaxf(ev2, SLOPEV*ev2);
      float p2 = ((w1 >> (j*4 + e)) & 1ull) ? __expf(ev2) : 0.f;
      if (am) p2 = 1.f;
      o[4+e] = p2 * inv;
    }
    f32x4 s0 = {o[0],o[1],o[2],o[3]};
    f32x4 s1 = {o[4],o[5],o[6],o[7]};
    __builtin_nontemporal_store(s0, (f32x4*)(attrow + c*CH + j*4));
    __builtin_nontemporal_store(s1, (f32x4*)(attrow + c*CH + 64 + j*4));
    bf16x4 p0, p1;
    #pragma unroll
    for (int e=0;e<4;e++){ p0[e] = (__bf16)o[e]; p1[e] = (__bf16)o[4+e]; }
    *(bf16x4*)((char*)pc + pof0) = p0;
    *(bf16x4*)((char*)pc + pof1) = p1;

    // THE barrier: vmcnt(5) retires staging(c) (issued+pinned at bottom of c-1)
    __builtin_amdgcn_sched_barrier(0);
    asm volatile("s_waitcnt vmcnt(5) lgkmcnt(0)" ::: "memory");
    __builtin_amdgcn_sched_barrier(0);
    __builtin_amdgcn_s_barrier();
    __builtin_amdgcn_sched_barrier(0);

    // MFMA chunk c: 4 k-slices
    const char* hcB = (const char*)hc;
    const char* pcB = (const char*)pc;
    #pragma unroll
    for (int ks=0;ks<4;ks++){
      int kb = (ks*64 + g*16) ^ csw;
      bf16x8 bf = *(const bf16x8*)(pcB + boff0 + kb);
      bf16x8 ah = *(const bf16x8*)(hcB + aoff0 + kb);
      acc = MFMA16(ah, bf, acc);
    }

    // staging for chunk c+1 AFTER the MFMA (WAR-safe: ordered by barrier(c)),
    // PINNED so it cannot sink past the next iteration's loads/stores.
    if (c+1 < NC){
      gload16(ghA + (c+1)*CH, &hn[wv*4][0]);
      gload16(ghB + (c+1)*CH, &hn[32 + wv*4][0]);
    }
    __builtin_amdgcn_sched_barrier(0);

    w0 = w0n; w1 = w1n; dva = dva_n; dvb = dvb_n;
  }

  // ---- epilogue ----
  int n = n0 + nh*16 + r15;
  size_t ob = (size_t)n*(HH*DD) + h*DD + cblk*16 + g*4;
  __builtin_nontemporal_store(acc, (f32x4*)(dout+ob));
}

extern "C" void kernel_launch(void* const* d_in, const int* in_sizes, int n_in,
                              void* d_out, int out_size, void* d_ws, size_t ws_size,
                              hipStream_t stream) {
  const float* h   = (const float*)d_in[0];
  const int*   adj = (const int*)d_in[1];
  const float* W   = (const float*)d_in[2];
  const float* a   = (const float*)d_in[3];
  float* out = (float*)d_out;

  short* wthi = (short*)d_ws;
  short* wtlo = wthi + (size_t)HH*DD*FF;
  short* hthi = wtlo + (size_t)HH*DD*FF;
  float* srcb = (float*)(hthi + (size_t)HH*DD*NN);
  float* dstb = srcb + HH*NN;
  u64*   padj = (u64*)(dstb + HH*NN);

  k_prep1<<<dim3(1152), 256, 0, stream>>>(W, adj, wthi, wtlo, padj);
  k_prep2<<<dim3(384), 256, 0, stream>>>(h, wthi, wtlo, a, srcb, dstb, hthi);
  k_att  <<<dim3(NN/32*HH), 512, 0, stream>>>(padj, srcb, dstb, hthi, out);
}